// Round 5
// baseline (107.105 us; speedup 1.0000x reference)
//
#include <hip/hip_runtime.h>
#include <math.h>

// Gaussians covariance, MI355X. cov = s^2 * I exactly (isotropic scales,
// R orthogonal) -> problem is the exact 3-NN search over N^2 pairs.
//
// R5 (vs R4: 43.6us, VGPR=28 proves array promotion FAILED -> ~2x VALU):
//  - named scalars via macros, IPT=8: one ds_read_b128 feeds 56 VALU
//  - 4-op ins4 (min + 3x v_med3_f32) -- exact sorted top-4 insert
//  - offset-space distance: J.w folded into first fma, +qi deferred to
//    epilogue -> 7 VALU/pair total (3 fma + 4 insert)
//  - explicit prefetch of sj[k+1], peeled last iter
//  - grid 6 x 128 = 768 blocks x 256 thr = exactly 3 blocks/CU
// Uniform top-4 everywhere: the self-pair (~0) is the global min, takes
// slot b0 at merge and is dropped; b1..b3 are the true 3-NN.
// NOTE: ~44us of the timed window is the harness's 256MiB d_ws poison fill.

#define N_PTS   12288
#define THREADS 256
#define IPT     8
#define ITILE   (THREADS * IPT)    // 2048 i's per block
#define NIT     (N_PTS / ITILE)    // 6 i-tiles
#define GSPLIT  128                // j-splits
#define JCH     (N_PTS / GSPLIT)   // 96 j's per block

__device__ __forceinline__ void ins4(float d, float& a0, float& a1,
                                     float& a2, float& a3) {
    // insert d into sorted a0<=a1<=a2<=a3, keep 4 smallest (4 VALU)
    const float n0 = fminf(a0, d);
    const float n1 = __builtin_amdgcn_fmed3f(a0, a1, d);
    const float n2 = __builtin_amdgcn_fmed3f(a1, a2, d);
    const float n3 = __builtin_amdgcn_fmed3f(a2, a3, d);
    a0 = n0; a1 = n1; a2 = n2; a3 = n3;
}

#define DECL(r) float px##r, py##r, pz##r, a0##r, a1##r, a2##r, a3##r;

#define LOADI(r) { \
    const int i_ = it * ITILE + (r) * THREADS + t; \
    px##r = pts[3 * i_ + 0]; \
    py##r = pts[3 * i_ + 1]; \
    pz##r = pts[3 * i_ + 2]; \
    a0##r = INFINITY; a1##r = INFINITY; a2##r = INFINITY; a3##r = INFINITY; }

// offset-space half-distance: d' = Jw - p.pj  (3 fma, J.w folded into #1);
// insert: 4 ops. True d^2/2 = d' + qi, added at epilogue.
#define PAIR(J, r) { \
    float d_ = fmaf(-(J).x, px##r, (J).w); \
    d_ = fmaf(-(J).y, py##r, d_); \
    d_ = fmaf(-(J).z, pz##r, d_); \
    ins4(d_, a0##r, a1##r, a2##r, a3##r); }

#define PAIRS(J) PAIR(J,0) PAIR(J,1) PAIR(J,2) PAIR(J,3) \
                 PAIR(J,4) PAIR(J,5) PAIR(J,6) PAIR(J,7)

#define STORE(r) { \
    const int i_ = it * ITILE + (r) * THREADS + t; \
    const float qi_ = 0.5f * fmaf(pz##r, pz##r, \
                       fmaf(py##r, py##r, px##r * px##r)); \
    ws4[(size_t)g * N_PTS + i_] = \
        make_float4(a0##r + qi_, a1##r + qi_, a2##r + qi_, a3##r + qi_); }

__global__ __launch_bounds__(THREADS) void knn_partial(
    const float* __restrict__ pts, float4* __restrict__ ws4)
{
    __shared__ float4 sj[JCH];     // 1.5 KB: (x, y, z, 0.5*|p|^2) per j
    const int t  = threadIdx.x;
    const int it = blockIdx.x;     // i-tile 0..5
    const int g  = blockIdx.y;     // j-split 0..127

    if (t < JCH) {
        const int j = g * JCH + t;
        const float x = pts[3 * j + 0];
        const float y = pts[3 * j + 1];
        const float z = pts[3 * j + 2];
        // same op order as qi_ in STORE -> self-distance cancels to ~eps
        sj[t] = make_float4(x, y, z, 0.5f * fmaf(z, z, fmaf(y, y, x * x)));
    }

    DECL(0) DECL(1) DECL(2) DECL(3) DECL(4) DECL(5) DECL(6) DECL(7)
    LOADI(0) LOADI(1) LOADI(2) LOADI(3)
    LOADI(4) LOADI(5) LOADI(6) LOADI(7)
    __syncthreads();

    float4 J = sj[0];
    #pragma unroll 2
    for (int k = 0; k < JCH - 1; ++k) {
        const float4 Jn = sj[k + 1];   // prefetch next j
        PAIRS(J)
        J = Jn;
    }
    PAIRS(J)                            // peeled last iteration

    STORE(0) STORE(1) STORE(2) STORE(3)
    STORE(4) STORE(5) STORE(6) STORE(7)
}

__global__ __launch_bounds__(256) void knn_merge(
    const float4* __restrict__ ws4, float* __restrict__ out)
{
    const int i = blockIdx.x * 256 + threadIdx.x;
    float b0 = INFINITY, b1 = INFINITY, b2 = INFINITY, b3 = INFINITY;
    #pragma unroll 4
    for (int g = 0; g < GSPLIT; ++g) {
        const float4 v = ws4[(size_t)g * N_PTS + i];   // coalesced
        ins4(v.x, b0, b1, b2, b3);
        ins4(v.y, b0, b1, b2, b3);
        ins4(v.z, b0, b1, b2, b3);
        ins4(v.w, b0, b1, b2, b3);
    }
    // b0 ~ 0 is the self-pair; b1..b3 are the 3-NN half squared distances
    const float d0 = sqrtf(fmaxf(b1 + b1, 0.0f));
    const float d1 = sqrtf(fmaxf(b2 + b2, 0.0f));
    const float d2 = sqrtf(fmaxf(b3 + b3, 0.0f));
    float mean = fmaxf((d0 + d1 + d2) * (1.0f / 3.0f), 1e-5f);
    const float s  = 0.001f * mean;
    const float s2 = s * s;

    float* o = out + (size_t)i * 9;
    o[0] = s2;   o[1] = 0.0f; o[2] = 0.0f;
    o[3] = 0.0f; o[4] = s2;   o[5] = 0.0f;
    o[6] = 0.0f; o[7] = 0.0f; o[8] = s2;
}

extern "C" void kernel_launch(void* const* d_in, const int* in_sizes, int n_in,
                              void* d_out, int out_size, void* d_ws, size_t ws_size,
                              hipStream_t stream) {
    const float* pts = (const float*)d_in[0];   // (N, 3) float32
    // d_in[1] = quaternions: algebraically irrelevant (cov = s^2 * I)
    float4* ws4 = (float4*)d_ws;                // 128 * 12288 * 16B = 25.2 MB
    float*  out = (float*)d_out;                // (N, 3, 3) float32

    knn_partial<<<dim3(NIT, GSPLIT), dim3(THREADS), 0, stream>>>(pts, ws4);
    knn_merge<<<dim3(N_PTS / 256), dim3(256), 0, stream>>>(ws4, out);
}

// Round 6
// 100.074 us; speedup vs baseline: 1.0703x; 1.0703x over previous
//
#include <hip/hip_runtime.h>
#include <math.h>

// Gaussians covariance, MI355X. cov = s^2 * I exactly (isotropic scales,
// R orthogonal) -> problem is the exact 3-NN search over N^2 pairs.
//
// R6 (vs R5: 43.2us at 7 VALU/pair, VALU-issue-bound at ~1.6GHz sustained):
//  Pass A: min-only per (i, cell) — 512 cells/i (128 j-chunks x 4 interleaved
//    substreams of 24 j's): 3 fma + 1 v_min = 4 VALU/pair. Cell id packed
//    into low 9 mantissa bits at epilogue (selection-only; ~2^-14 perturb).
//  Pass B: top-4 cells by packed minima — provably contains the cells of
//    {self, d1, d2, d3} (containing cells' minima <= d3, all others >= d4;
//    ties harmless) — then EXACT diff-form rescan of 4x24=96 j's, top-4
//    insert, drop the exact-0 self pair. 192 blocks (fixes R5's 48-block
//    merge bottleneck).
// NOTE: ~44us of the timed window is the harness's 256MiB d_ws poison fill.

#define N_PTS   12288
#define THREADS 256
#define IPT     8
#define ITILE   (THREADS * IPT)    // 2048 i's per block
#define NIT     (N_PTS / ITILE)    // 6 i-tiles
#define GSPLIT  128                // j-chunks
#define JCH     (N_PTS / GSPLIT)   // 96 j's per chunk
#define NSUB    4                  // substreams per chunk
#define CELL    (JCH / NSUB)       // 24 j's per cell
#define NCELL   (GSPLIT * NSUB)    // 512 cells

__device__ __forceinline__ void ins4(float d, float& a0, float& a1,
                                     float& a2, float& a3) {
    // insert d into sorted a0<=a1<=a2<=a3, keep 4 smallest (4 VALU)
    const float n0 = fminf(a0, d);
    const float n1 = __builtin_amdgcn_fmed3f(a0, a1, d);
    const float n2 = __builtin_amdgcn_fmed3f(a1, a2, d);
    const float n3 = __builtin_amdgcn_fmed3f(a2, a3, d);
    a0 = n0; a1 = n1; a2 = n2; a3 = n3;
}

#define DECL(r) float px##r, py##r, pz##r, m0##r, m1##r, m2##r, m3##r;

#define LOADI(r) { \
    const int i_ = it * ITILE + (r) * THREADS + t; \
    px##r = pts[3 * i_ + 0]; \
    py##r = pts[3 * i_ + 1]; \
    pz##r = pts[3 * i_ + 2]; \
    m0##r = INFINITY; m1##r = INFINITY; m2##r = INFINITY; m3##r = INFINITY; }

// offset-space half-distance d' = Jw - p.pj (3 fma) + running min (1 op)
#define P(J, s, r) { \
    float d_ = fmaf(-(J).x, px##r, (J).w); \
    d_ = fmaf(-(J).y, py##r, d_); \
    d_ = fmaf(-(J).z, pz##r, d_); \
    m##s##r = fminf(m##s##r, d_); }

#define GROUP(J, s) P(J,s,0) P(J,s,1) P(J,s,2) P(J,s,3) \
                    P(J,s,4) P(J,s,5) P(J,s,6) P(J,s,7)

#define PACK(m, s) __uint_as_float((__float_as_uint(m) & ~511u) | (4u*g + (s)))

#define STORE(r) { \
    const int i_ = it * ITILE + (r) * THREADS + t; \
    ws4[(size_t)g * N_PTS + i_] = make_float4( \
        PACK(m0##r, 0), PACK(m1##r, 1), PACK(m2##r, 2), PACK(m3##r, 3)); }

__global__ __launch_bounds__(THREADS) void knn_cellmin(
    const float* __restrict__ pts, float4* __restrict__ ws4)
{
    __shared__ float4 sj[JCH];     // 1.5 KB: (x, y, z, 0.5*|p|^2) per j
    const int t  = threadIdx.x;
    const int it = blockIdx.x;     // i-tile 0..5
    const int g  = blockIdx.y;     // j-chunk 0..127

    if (t < JCH) {
        const int j = g * JCH + t;
        const float x = pts[3 * j + 0];
        const float y = pts[3 * j + 1];
        const float z = pts[3 * j + 2];
        sj[t] = make_float4(x, y, z, 0.5f * fmaf(z, z, fmaf(y, y, x * x)));
    }

    DECL(0) DECL(1) DECL(2) DECL(3) DECL(4) DECL(5) DECL(6) DECL(7)
    LOADI(0) LOADI(1) LOADI(2) LOADI(3)
    LOADI(4) LOADI(5) LOADI(6) LOADI(7)
    __syncthreads();

    float4 J0 = sj[0], J1 = sj[1], J2 = sj[2], J3 = sj[3];
    #pragma unroll 2
    for (int k = 0; k < JCH - 4; k += 4) {
        const float4 N0 = sj[k + 4];   // prefetch next group
        const float4 N1 = sj[k + 5];
        const float4 N2 = sj[k + 6];
        const float4 N3 = sj[k + 7];
        GROUP(J0, 0) GROUP(J1, 1) GROUP(J2, 2) GROUP(J3, 3)
        J0 = N0; J1 = N1; J2 = N2; J3 = N3;
    }
    GROUP(J0, 0) GROUP(J1, 1) GROUP(J2, 2) GROUP(J3, 3)   // peeled tail

    STORE(0) STORE(1) STORE(2) STORE(3)
    STORE(4) STORE(5) STORE(6) STORE(7)
}

__global__ __launch_bounds__(64) void knn_rescan(
    const float4* __restrict__ ws4, const float* __restrict__ pts,
    float* __restrict__ out)
{
    const int i = blockIdx.x * 64 + threadIdx.x;

    // top-4 cells by packed minima (value order == distance order up to
    // the 2^-14 packing perturbation; ids in low bits break ties)
    float c0 = INFINITY, c1 = INFINITY, c2 = INFINITY, c3 = INFINITY;
    #pragma unroll 4
    for (int g = 0; g < GSPLIT; ++g) {
        const float4 v = ws4[(size_t)g * N_PTS + i];   // coalesced
        ins4(v.x, c0, c1, c2, c3);
        ins4(v.y, c0, c1, c2, c3);
        ins4(v.z, c0, c1, c2, c3);
        ins4(v.w, c0, c1, c2, c3);
    }

    const float px = pts[3 * i + 0];
    const float py = pts[3 * i + 1];
    const float pz = pts[3 * i + 2];

    // exact diff-form rescan of the 4 candidate cells (96 pairs)
    float b0 = INFINITY, b1 = INFINITY, b2 = INFINITY, b3 = INFINITY;
    const unsigned cells[4] = {
        __float_as_uint(c0) & 511u, __float_as_uint(c1) & 511u,
        __float_as_uint(c2) & 511u, __float_as_uint(c3) & 511u };
    #pragma unroll
    for (int q = 0; q < 4; ++q) {
        const int base = (int)(cells[q] >> 2) * JCH + (int)(cells[q] & 3u);
        #pragma unroll 4
        for (int n = 0; n < CELL; ++n) {
            const int j = base + NSUB * n;
            const float dx = px - pts[3 * j + 0];
            const float dy = py - pts[3 * j + 1];
            const float dz = pz - pts[3 * j + 2];
            const float d2 = fmaf(dz, dz, fmaf(dy, dy, dx * dx));
            ins4(d2, b0, b1, b2, b3);    // j==i gives exactly 0 -> b0
        }
    }

    // b0 == 0 is the self pair; b1..b3 are the true 3-NN squared distances
    const float d0 = sqrtf(b1);
    const float d1 = sqrtf(b2);
    const float d2 = sqrtf(b3);
    float mean = fmaxf((d0 + d1 + d2) * (1.0f / 3.0f), 1e-5f);
    const float s  = 0.001f * mean;
    const float s2 = s * s;

    float* o = out + (size_t)i * 9;
    o[0] = s2;   o[1] = 0.0f; o[2] = 0.0f;
    o[3] = 0.0f; o[4] = s2;   o[5] = 0.0f;
    o[6] = 0.0f; o[7] = 0.0f; o[8] = s2;
}

extern "C" void kernel_launch(void* const* d_in, const int* in_sizes, int n_in,
                              void* d_out, int out_size, void* d_ws, size_t ws_size,
                              hipStream_t stream) {
    const float* pts = (const float*)d_in[0];   // (N, 3) float32
    // d_in[1] = quaternions: algebraically irrelevant (cov = s^2 * I)
    float4* ws4 = (float4*)d_ws;                // 128 * 12288 * 16B = 25.2 MB
    float*  out = (float*)d_out;                // (N, 3, 3) float32

    knn_cellmin<<<dim3(NIT, GSPLIT), dim3(THREADS), 0, stream>>>(pts, ws4);
    knn_rescan<<<dim3(N_PTS / 64), dim3(64), 0, stream>>>(ws4, pts, out);
}

// Round 7
// 86.754 us; speedup vs baseline: 1.2346x; 1.1535x over previous
//
#include <hip/hip_runtime.h>
#include <math.h>

// Gaussians covariance, MI355X. cov = s^2 * I exactly (isotropic scales,
// R orthogonal) -> problem is the exact 3-NN search over N^2 pairs.
//
// R7: pass A moved to the MATRIX pipe. One mfma_f32_16x16x32_f16 computes a
// 16x16 tile of offset-half-distances D[i][j] = qj - xi.xj via compensated
// fp16 (hi/lo split: K slots ah*bh, al*bh, ah*bl, 1*qh, 1*ql = 11 of 32;
// fp16 products are exact in fp32 -> selection error ~4e-5, effectively
// exact). Remaining VALU: 1 v_min per pair (cell = (chunk, j mod 16) = the
// D column lane, so the register running-min IS the cell min; no cross-lane
// reduction). qi re-added per row before packing the 9-bit cell id into the
// mantissa. Pass B: 16 workers/i (768 blocks x 256 thr = 12 waves/CU) merge
// 384 cell minima, then 4 workers/i exact-rescan the top-4 cells (128 j);
// self-pair is exactly 0, dropped.
// NOTE: ~46us of the timed window is the harness's 256MiB d_ws poison fill.

#define N_PTS 12288
#define CHUNK 512               // j's per chunk
#define NCH   (N_PTS / CHUNK)   // 24 chunks
#define NCELL (NCH * 16)        // 384 cells; cell=(g, j mod 16), 32 j's each
#define CELLJ 32
#define IBLK  256               // i's per pass-A block
#define NIB   (N_PTS / IBLK)    // 48

typedef _Float16 half8 __attribute__((ext_vector_type(8)));
typedef float    f32x4 __attribute__((ext_vector_type(4)));

__device__ __forceinline__ void ins4(float d, float& a0, float& a1,
                                     float& a2, float& a3) {
    // insert d into sorted a0<=a1<=a2<=a3, keep 4 smallest (4 VALU)
    const float n0 = fminf(a0, d);
    const float n1 = __builtin_amdgcn_fmed3f(a0, a1, d);
    const float n2 = __builtin_amdgcn_fmed3f(a1, a2, d);
    const float n3 = __builtin_amdgcn_fmed3f(a2, a3, d);
    a0 = n0; a1 = n1; a2 = n2; a3 = n3;
}

__global__ __launch_bounds__(256) void cellmin_mfma(
    const float* __restrict__ pts, unsigned* __restrict__ ws)
{
    // B-fragment store, native layout: [32 j-blocks][64 lane-slots][8 halves]
    // slots 0-15 = quad0 cols, 16-31 = quad1 cols, 32-63 = zeros (K pad)
    __shared__ _Float16 sB[32 * 64 * 8];   // 32 KB
    __shared__ float    sqi[IBLK];         // 1 KB

    const int t    = threadIdx.x;
    const int iblk = blockIdx.x * IBLK;
    const int g    = blockIdx.y;           // chunk 0..23

    // ---- stage this chunk's B fragments (hi/lo split + qh/ql) ----
    for (int jl = t; jl < CHUNK; jl += 256) {
        const int j = g * CHUNK + jl;
        const float x = pts[3 * j + 0], y = pts[3 * j + 1], z = pts[3 * j + 2];
        const _Float16 bhx = (_Float16)x, bhy = (_Float16)y, bhz = (_Float16)z;
        const _Float16 blx = (_Float16)(x - (float)bhx);
        const _Float16 bly = (_Float16)(y - (float)bhy);
        const _Float16 blz = (_Float16)(z - (float)bhz);
        const float q = 0.5f * fmaf(z, z, fmaf(y, y, x * x));
        const _Float16 qh = (_Float16)q;
        const _Float16 ql = (_Float16)(q - (float)qh);
        const int b = jl >> 4, col = jl & 15;
        half8 s0;   // k0-7: -bh(xyz) (vs ah), -bh(xyz) (vs al), -bl(x,y) (vs ah)
        s0[0] = -bhx; s0[1] = -bhy; s0[2] = -bhz;
        s0[3] = -bhx; s0[4] = -bhy; s0[5] = -bhz;
        s0[6] = -blx; s0[7] = -bly;
        half8 s1;   // k8-15: -bl_z (vs ah_z), qh, ql (vs 1), zeros
        s1 = (_Float16)0;
        s1[0] = -blz; s1[1] = qh; s1[2] = ql;
        *(half8*)&sB[(b * 64 + col) * 8]      = s0;
        *(half8*)&sB[(b * 64 + 16 + col) * 8] = s1;
    }
    {   // zero-fill quads 2-3 slots
        half8 zz = (_Float16)0;
        for (int s = t; s < 32 * 32; s += 256)
            *(half8*)&sB[((s >> 5) * 64 + 32 + (s & 31)) * 8] = zz;
    }
    {   // qi for this block's 256 i's (fp32, de-offsets before packing)
        const int i = iblk + t;
        const float x = pts[3 * i + 0], y = pts[3 * i + 1], z = pts[3 * i + 2];
        sqi[t] = 0.5f * fmaf(z, z, fmaf(y, y, x * x));
    }

    // ---- A fragments: wave w owns i-tiles 4w+rr (16 i's each) ----
    const int lane = t & 63;
    const int w    = t >> 6;
    const int m    = lane & 15;    // A row / D col
    const int quad = lane >> 4;

    half8 afr[4];
    f32x4 mn[4];
    #pragma unroll
    for (int rr = 0; rr < 4; ++rr) {
        const int i = iblk + (4 * w + rr) * 16 + m;
        const float x = pts[3 * i + 0], y = pts[3 * i + 1], z = pts[3 * i + 2];
        const _Float16 ahx = (_Float16)x, ahy = (_Float16)y, ahz = (_Float16)z;
        const _Float16 alx = (_Float16)(x - (float)ahx);
        const _Float16 aly = (_Float16)(y - (float)ahy);
        const _Float16 alz = (_Float16)(z - (float)ahz);
        half8 a = (_Float16)0;
        if (quad == 0) {        // k0-7: ah(xyz), al(xyz), ah(x,y)
            a[0] = ahx; a[1] = ahy; a[2] = ahz;
            a[3] = alx; a[4] = aly; a[5] = alz;
            a[6] = ahx; a[7] = ahy;
        } else if (quad == 1) { // k8-15: ah_z, 1, 1, zeros
            a[0] = ahz; a[1] = (_Float16)1.0f; a[2] = (_Float16)1.0f;
        }
        afr[rr] = a;
        mn[rr] = INFINITY;
    }
    __syncthreads();

    const f32x4 zero4 = 0.0f;
    #pragma unroll 4
    for (int b = 0; b < 32; ++b) {
        const half8 bf = *(const half8*)&sB[(b * 64 + lane) * 8];
        #pragma unroll
        for (int rr = 0; rr < 4; ++rr) {
            const f32x4 d = __builtin_amdgcn_mfma_f32_16x16x32_f16(
                afr[rr], bf, zero4, 0, 0, 0);
            mn[rr][0] = fminf(mn[rr][0], d[0]);
            mn[rr][1] = fminf(mn[rr][1], d[1]);
            mn[rr][2] = fminf(mn[rr][2], d[2]);
            mn[rr][3] = fminf(mn[rr][3], d[3]);
        }
    }

    // ---- +qi, pack 9-bit cell id into mantissa, scattered store ----
    const unsigned cid = (unsigned)(g * 16 + m);   // D col == cell lane
    #pragma unroll
    for (int rr = 0; rr < 4; ++rr) {
        const int rowb = (4 * w + rr) * 16 + quad * 4;   // D row base
        const float4 qf = *(const float4*)&sqi[rowb];
        #pragma unroll
        for (int reg = 0; reg < 4; ++reg) {
            const float v = mn[rr][reg] + (&qf.x)[reg];
            const unsigned u = (__float_as_uint(v) & ~511u) | cid;
            ws[(size_t)cid * N_PTS + (iblk + rowb + reg)] = u;
        }
    }
}

__global__ __launch_bounds__(256) void knn_finalize(
    const unsigned* __restrict__ ws, const float* __restrict__ pts,
    float* __restrict__ out)
{
    __shared__ float cand[16][16][4];   // [worker][i_loc][top4]
    __shared__ int   cids[16][4];
    __shared__ float rc[4][16][4];

    const int t     = threadIdx.x;
    const int il    = t & 15, w = t >> 4;   // 16 workers per i
    const int ibase = blockIdx.x * 16;

    // phase 1: each worker scans 24 of the 384 packed cell minima
    {
        const int i = ibase + il;
        float c0 = INFINITY, c1 = INFINITY, c2 = INFINITY, c3 = INFINITY;
        #pragma unroll 4
        for (int c = w * 24; c < w * 24 + 24; ++c) {
            const float v = __uint_as_float(ws[(size_t)c * N_PTS + i]);
            ins4(v, c0, c1, c2, c3);
        }
        cand[w][il][0] = c0; cand[w][il][1] = c1;
        cand[w][il][2] = c2; cand[w][il][3] = c3;
    }
    __syncthreads();

    // phase 2: merge 16 worker lists -> top-4 cell ids per i
    if (t < 16) {
        float b0 = INFINITY, b1 = INFINITY, b2 = INFINITY, b3 = INFINITY;
        #pragma unroll 4
        for (int ww = 0; ww < 16; ++ww) {
            ins4(cand[ww][t][0], b0, b1, b2, b3);
            ins4(cand[ww][t][1], b0, b1, b2, b3);
            ins4(cand[ww][t][2], b0, b1, b2, b3);
            ins4(cand[ww][t][3], b0, b1, b2, b3);
        }
        cids[t][0] = (int)(__float_as_uint(b0) & 511u);
        cids[t][1] = (int)(__float_as_uint(b1) & 511u);
        cids[t][2] = (int)(__float_as_uint(b2) & 511u);
        cids[t][3] = (int)(__float_as_uint(b3) & 511u);
    }
    __syncthreads();

    // phase 3: 4 workers/i exact diff-form rescan of one candidate cell each
    if (t < 64) {
        const int q  = t >> 4;
        const int i2 = ibase + (t & 15);
        const int cid = cids[t & 15][q];
        const float px = pts[3 * i2 + 0], py = pts[3 * i2 + 1], pz = pts[3 * i2 + 2];
        const int jb = (cid >> 4) * CHUNK + (cid & 15);
        float b0 = INFINITY, b1 = INFINITY, b2 = INFINITY, b3 = INFINITY;
        #pragma unroll 4
        for (int n = 0; n < CELLJ; ++n) {
            const int j = jb + n * 16;
            const float dx = px - pts[3 * j + 0];
            const float dy = py - pts[3 * j + 1];
            const float dz = pz - pts[3 * j + 2];
            const float d2 = fmaf(dz, dz, fmaf(dy, dy, dx * dx));
            ins4(d2, b0, b1, b2, b3);       // j==i gives exactly 0
        }
        rc[q][t & 15][0] = b0; rc[q][t & 15][1] = b1;
        rc[q][t & 15][2] = b2; rc[q][t & 15][3] = b3;
    }
    __syncthreads();

    // phase 4: final merge, drop the exact-0 self pair, emit s^2 * I
    if (t < 16) {
        float b0 = INFINITY, b1 = INFINITY, b2 = INFINITY, b3 = INFINITY;
        #pragma unroll
        for (int q = 0; q < 4; ++q) {
            ins4(rc[q][t][0], b0, b1, b2, b3);
            ins4(rc[q][t][1], b0, b1, b2, b3);
            ins4(rc[q][t][2], b0, b1, b2, b3);
            ins4(rc[q][t][3], b0, b1, b2, b3);
        }
        const float d0 = sqrtf(b1);
        const float d1 = sqrtf(b2);
        const float d2 = sqrtf(b3);
        float mean = fmaxf((d0 + d1 + d2) * (1.0f / 3.0f), 1e-5f);
        const float s  = 0.001f * mean;
        const float s2 = s * s;
        float* o = out + (size_t)(ibase + t) * 9;
        o[0] = s2;   o[1] = 0.0f; o[2] = 0.0f;
        o[3] = 0.0f; o[4] = s2;   o[5] = 0.0f;
        o[6] = 0.0f; o[7] = 0.0f; o[8] = s2;
    }
}

extern "C" void kernel_launch(void* const* d_in, const int* in_sizes, int n_in,
                              void* d_out, int out_size, void* d_ws, size_t ws_size,
                              hipStream_t stream) {
    const float* pts = (const float*)d_in[0];   // (N, 3) float32
    // d_in[1] = quaternions: algebraically irrelevant (cov = s^2 * I)
    unsigned* ws = (unsigned*)d_ws;             // 384 * 12288 * 4B = 18.9 MB
    float*    out = (float*)d_out;              // (N, 3, 3) float32

    cellmin_mfma<<<dim3(NIB, NCH), dim3(256), 0, stream>>>(pts, ws);
    knn_finalize<<<dim3(N_PTS / 16), dim3(256), 0, stream>>>(ws, pts, out);
}

// Round 8
// 85.861 us; speedup vs baseline: 1.2474x; 1.0104x over previous
//
#include <hip/hip_runtime.h>
#include <math.h>

// Gaussians covariance, MI355X. cov = s^2 * I exactly (isotropic scales,
// R orthogonal) -> problem is the exact 3-NN search over N^2 pairs.
//
// R8 (vs R7: ~42.6us controllable; pass-A epilogue did scattered per-lane
// dword stores -> 16 cache lines per wave-store, ~75MB partial-line RMW
// traffic vs 18.9MB payload):
//  - pass A now transposes the 16 per-lane cell minima through LDS (reusing
//    the 32KB B-fragment buffer, stride 257 to spread banks) and emits 16
//    fully-coalesced 1KB stores per thread; qi lives in a register (thread t
//    owns i = iblk + t); cell id is wave-uniform at pack time.
//  - pass A core unchanged: one mfma_f32_16x16x32_f16 = 16x16 tile of
//    offset-half-distances qj - xi.xj via compensated fp16 (exact products;
//    selection error ~4e-5), 1 v_min per pair, cell = (chunk, j mod 16) =
//    D column lane -> no cross-lane reduction.
//  - pass B unchanged: 16 workers/i merge 384 packed cell minima, 4
//    workers/i exact diff-form rescan of the top-4 cells, self-pair (exact
//    0) dropped, emit s^2 * I.
// NOTE: ~44us of the timed window is the harness's 256MiB d_ws poison fill.

#define N_PTS 12288
#define CHUNK 512               // j's per chunk
#define NCH   (N_PTS / CHUNK)   // 24 chunks
#define NCELL (NCH * 16)        // 384 cells; cell=(g, j mod 16), 32 j's each
#define CELLJ 32
#define IBLK  256               // i's per pass-A block
#define NIB   (N_PTS / IBLK)    // 48
#define TSTR  257               // LDS transpose stride (dwords)

typedef _Float16 half8 __attribute__((ext_vector_type(8)));
typedef float    f32x4 __attribute__((ext_vector_type(4)));

__device__ __forceinline__ void ins4(float d, float& a0, float& a1,
                                     float& a2, float& a3) {
    // insert d into sorted a0<=a1<=a2<=a3, keep 4 smallest (4 VALU)
    const float n0 = fminf(a0, d);
    const float n1 = __builtin_amdgcn_fmed3f(a0, a1, d);
    const float n2 = __builtin_amdgcn_fmed3f(a1, a2, d);
    const float n3 = __builtin_amdgcn_fmed3f(a2, a3, d);
    a0 = n0; a1 = n1; a2 = n2; a3 = n3;
}

__global__ __launch_bounds__(256) void cellmin_mfma(
    const float* __restrict__ pts, unsigned* __restrict__ ws)
{
    // 32KB shared: B fragments during the MFMA loop, then reused as the
    // [16 cells][256 i] transpose buffer (stride TSTR) for coalesced stores
    __shared__ __align__(16) unsigned char shmem[32 * 64 * 8 * 2];
    _Float16* sB = (_Float16*)shmem;
    float*    sT = (float*)shmem;

    const int t    = threadIdx.x;
    const int iblk = blockIdx.x * IBLK;
    const int g    = blockIdx.y;           // chunk 0..23

    // ---- stage this chunk's B fragments (hi/lo split + qh/ql) ----
    // native layout: [32 j-blocks][64 lane-slots][8 halves];
    // slots 0-15 = quad0 cols (k0-7), 16-31 = quad1 cols (k8-15), 32-63 = 0
    for (int jl = t; jl < CHUNK; jl += 256) {
        const int j = g * CHUNK + jl;
        const float x = pts[3 * j + 0], y = pts[3 * j + 1], z = pts[3 * j + 2];
        const _Float16 bhx = (_Float16)x, bhy = (_Float16)y, bhz = (_Float16)z;
        const _Float16 blx = (_Float16)(x - (float)bhx);
        const _Float16 bly = (_Float16)(y - (float)bhy);
        const _Float16 blz = (_Float16)(z - (float)bhz);
        const float q = 0.5f * fmaf(z, z, fmaf(y, y, x * x));
        const _Float16 qh = (_Float16)q;
        const _Float16 ql = (_Float16)(q - (float)qh);
        const int b = jl >> 4, col = jl & 15;
        half8 s0;   // k0-7: -bh(xyz) (vs ah), -bh(xyz) (vs al), -bl(x,y)
        s0[0] = -bhx; s0[1] = -bhy; s0[2] = -bhz;
        s0[3] = -bhx; s0[4] = -bhy; s0[5] = -bhz;
        s0[6] = -blx; s0[7] = -bly;
        half8 s1;   // k8-15: -bl_z (vs ah_z), qh, ql (vs 1), zeros
        s1 = (_Float16)0;
        s1[0] = -blz; s1[1] = qh; s1[2] = ql;
        *(half8*)&sB[(b * 64 + col) * 8]      = s0;
        *(half8*)&sB[(b * 64 + 16 + col) * 8] = s1;
    }
    {   // zero-fill quads 2-3 slots
        half8 zz = (_Float16)0;
        for (int s = t; s < 32 * 32; s += 256)
            *(half8*)&sB[((s >> 5) * 64 + 32 + (s & 31)) * 8] = zz;
    }

    // own-i q (thread t owns i = iblk + t for the store phase)
    float qi_t;
    {
        const float x = pts[3 * (iblk + t) + 0];
        const float y = pts[3 * (iblk + t) + 1];
        const float z = pts[3 * (iblk + t) + 2];
        qi_t = 0.5f * fmaf(z, z, fmaf(y, y, x * x));
    }

    // ---- A fragments: wave w owns i-tiles 4w+rr (16 i's each) ----
    const int lane = t & 63;
    const int w    = t >> 6;
    const int m    = lane & 15;    // A row / D col == cell lane
    const int quad = lane >> 4;

    half8 afr[4];
    f32x4 mn[4];
    #pragma unroll
    for (int rr = 0; rr < 4; ++rr) {
        const int i = iblk + (4 * w + rr) * 16 + m;
        const float x = pts[3 * i + 0], y = pts[3 * i + 1], z = pts[3 * i + 2];
        const _Float16 ahx = (_Float16)x, ahy = (_Float16)y, ahz = (_Float16)z;
        const _Float16 alx = (_Float16)(x - (float)ahx);
        const _Float16 aly = (_Float16)(y - (float)ahy);
        const _Float16 alz = (_Float16)(z - (float)ahz);
        half8 a = (_Float16)0;
        if (quad == 0) {        // k0-7: ah(xyz), al(xyz), ah(x,y)
            a[0] = ahx; a[1] = ahy; a[2] = ahz;
            a[3] = alx; a[4] = aly; a[5] = alz;
            a[6] = ahx; a[7] = ahy;
        } else if (quad == 1) { // k8-15: ah_z, 1, 1, zeros
            a[0] = ahz; a[1] = (_Float16)1.0f; a[2] = (_Float16)1.0f;
        }
        afr[rr] = a;
        mn[rr] = INFINITY;
    }
    __syncthreads();

    const f32x4 zero4 = 0.0f;
    #pragma unroll 4
    for (int b = 0; b < 32; ++b) {
        const half8 bf = *(const half8*)&sB[(b * 64 + lane) * 8];
        #pragma unroll
        for (int rr = 0; rr < 4; ++rr) {
            const f32x4 d = __builtin_amdgcn_mfma_f32_16x16x32_f16(
                afr[rr], bf, zero4, 0, 0, 0);
            mn[rr][0] = fminf(mn[rr][0], d[0]);
            mn[rr][1] = fminf(mn[rr][1], d[1]);
            mn[rr][2] = fminf(mn[rr][2], d[2]);
            mn[rr][3] = fminf(mn[rr][3], d[3]);
        }
    }
    __syncthreads();   // done with sB; reuse as transpose buffer

    // ---- transpose through LDS: sT[cell][i_loc], stride TSTR ----
    #pragma unroll
    for (int rr = 0; rr < 4; ++rr) {
        const int rowb = (4 * w + rr) * 16 + quad * 4;   // D row base
        #pragma unroll
        for (int reg = 0; reg < 4; ++reg)
            sT[m * TSTR + rowb + reg] = mn[rr][reg];
    }
    __syncthreads();

    // ---- coalesced packed stores: 16 x 1KB per-cell rows ----
    #pragma unroll
    for (int c = 0; c < 16; ++c) {
        const float v = sT[c * TSTR + t] + qi_t;
        const unsigned cid = (unsigned)(g * 16 + c);     // wave-uniform
        ws[(size_t)cid * N_PTS + iblk + t] =
            (__float_as_uint(v) & ~511u) | cid;
    }
}

__global__ __launch_bounds__(256) void knn_finalize(
    const unsigned* __restrict__ ws, const float* __restrict__ pts,
    float* __restrict__ out)
{
    __shared__ float cand[16][16][4];   // [worker][i_loc][top4]
    __shared__ int   cids[16][4];
    __shared__ float rc[4][16][4];

    const int t     = threadIdx.x;
    const int il    = t & 15, w = t >> 4;   // 16 workers per i
    const int ibase = blockIdx.x * 16;

    // phase 1: each worker scans 24 of the 384 packed cell minima
    {
        const int i = ibase + il;
        float c0 = INFINITY, c1 = INFINITY, c2 = INFINITY, c3 = INFINITY;
        #pragma unroll 4
        for (int c = w * 24; c < w * 24 + 24; ++c) {
            const float v = __uint_as_float(ws[(size_t)c * N_PTS + i]);
            ins4(v, c0, c1, c2, c3);
        }
        cand[w][il][0] = c0; cand[w][il][1] = c1;
        cand[w][il][2] = c2; cand[w][il][3] = c3;
    }
    __syncthreads();

    // phase 2: merge 16 worker lists -> top-4 cell ids per i
    if (t < 16) {
        float b0 = INFINITY, b1 = INFINITY, b2 = INFINITY, b3 = INFINITY;
        #pragma unroll 4
        for (int ww = 0; ww < 16; ++ww) {
            ins4(cand[ww][t][0], b0, b1, b2, b3);
            ins4(cand[ww][t][1], b0, b1, b2, b3);
            ins4(cand[ww][t][2], b0, b1, b2, b3);
            ins4(cand[ww][t][3], b0, b1, b2, b3);
        }
        cids[t][0] = (int)(__float_as_uint(b0) & 511u);
        cids[t][1] = (int)(__float_as_uint(b1) & 511u);
        cids[t][2] = (int)(__float_as_uint(b2) & 511u);
        cids[t][3] = (int)(__float_as_uint(b3) & 511u);
    }
    __syncthreads();

    // phase 3: 4 workers/i exact diff-form rescan of one candidate cell each
    if (t < 64) {
        const int q  = t >> 4;
        const int i2 = ibase + (t & 15);
        const int cid = cids[t & 15][q];
        const float px = pts[3 * i2 + 0], py = pts[3 * i2 + 1], pz = pts[3 * i2 + 2];
        const int jb = (cid >> 4) * CHUNK + (cid & 15);
        float b0 = INFINITY, b1 = INFINITY, b2 = INFINITY, b3 = INFINITY;
        #pragma unroll 4
        for (int n = 0; n < CELLJ; ++n) {
            const int j = jb + n * 16;
            const float dx = px - pts[3 * j + 0];
            const float dy = py - pts[3 * j + 1];
            const float dz = pz - pts[3 * j + 2];
            const float d2 = fmaf(dz, dz, fmaf(dy, dy, dx * dx));
            ins4(d2, b0, b1, b2, b3);       // j==i gives exactly 0
        }
        rc[q][t & 15][0] = b0; rc[q][t & 15][1] = b1;
        rc[q][t & 15][2] = b2; rc[q][t & 15][3] = b3;
    }
    __syncthreads();

    // phase 4: final merge, drop the exact-0 self pair, emit s^2 * I
    if (t < 16) {
        float b0 = INFINITY, b1 = INFINITY, b2 = INFINITY, b3 = INFINITY;
        #pragma unroll
        for (int q = 0; q < 4; ++q) {
            ins4(rc[q][t][0], b0, b1, b2, b3);
            ins4(rc[q][t][1], b0, b1, b2, b3);
            ins4(rc[q][t][2], b0, b1, b2, b3);
            ins4(rc[q][t][3], b0, b1, b2, b3);
        }
        const float d0 = sqrtf(b1);
        const float d1 = sqrtf(b2);
        const float d2 = sqrtf(b3);
        float mean = fmaxf((d0 + d1 + d2) * (1.0f / 3.0f), 1e-5f);
        const float s  = 0.001f * mean;
        const float s2 = s * s;
        float* o = out + (size_t)(ibase + t) * 9;
        o[0] = s2;   o[1] = 0.0f; o[2] = 0.0f;
        o[3] = 0.0f; o[4] = s2;   o[5] = 0.0f;
        o[6] = 0.0f; o[7] = 0.0f; o[8] = s2;
    }
}

extern "C" void kernel_launch(void* const* d_in, const int* in_sizes, int n_in,
                              void* d_out, int out_size, void* d_ws, size_t ws_size,
                              hipStream_t stream) {
    const float* pts = (const float*)d_in[0];   // (N, 3) float32
    // d_in[1] = quaternions: algebraically irrelevant (cov = s^2 * I)
    unsigned* ws = (unsigned*)d_ws;             // 384 * 12288 * 4B = 18.9 MB
    float*    out = (float*)d_out;              // (N, 3, 3) float32

    cellmin_mfma<<<dim3(NIB, NCH), dim3(256), 0, stream>>>(pts, ws);
    knn_finalize<<<dim3(N_PTS / 16), dim3(256), 0, stream>>>(ws, pts, out);
}